// Round 1
// baseline (275.305 us; speedup 1.0000x reference)
//
#include <hip/hip_runtime.h>
#include <cstdint>

#define B_ 4
#define C_ 128
#define INNER_ 64
#define N_ 4096

typedef __attribute__((ext_vector_type(8))) short short8;
typedef __attribute__((ext_vector_type(4))) float f32x4;

__device__ __forceinline__ short f2bf(float f) {
  unsigned u = __builtin_bit_cast(unsigned, f);
  unsigned r = (u + 0x7FFFu + ((u >> 16) & 1u)) >> 16;
  return (short)r;
}

// ---------------------------------------------------------------------------
// Kernel 1: QKV 1x1-conv.  Out: qb/kb as [B][N][64] bf16, vb as [B][C][N] bf16.
// grid = B * (N/64) = 256 blocks, 256 threads (4 waves).
// ---------------------------------------------------------------------------
__global__ __launch_bounds__(256) void qkv_kernel(
    const float* __restrict__ x,
    const float* __restrict__ Wq, const float* __restrict__ bq,
    const float* __restrict__ Wk, const float* __restrict__ bk,
    const float* __restrict__ Wv, const float* __restrict__ bv,
    short* __restrict__ qb, short* __restrict__ kb, short* __restrict__ vb)
{
  __shared__ short xT[64 * 136];  // [n][c], pad 128->136 (16B-aligned rows)
  const int tid = threadIdx.x;
  const int b   = blockIdx.x >> 6;
  const int n0  = (blockIdx.x & 63) << 6;

  // stage x[b, :, n0:n0+64] into LDS transposed, bf16
  const float* xb = x + (size_t)b * C_ * N_ + n0;
  for (int i = tid; i < 64 * C_; i += 256) {
    int nn = i & 63, c = i >> 6;
    xT[nn * 136 + c] = f2bf(xb[(size_t)c * N_ + nn]);
  }
  __syncthreads();

  const int w = tid >> 6, lane = tid & 63, quad = lane >> 4, l16 = lane & 15;

  for (int oi = 0; oi < 4; ++oi) {
    const int ot = w + oi * 4;          // 16 col-tiles total, wave-striped
    const int o  = ot * 16 + l16;       // 0..255 (q:0-63, k:64-127, v:128-255)
    const float* wrow;
    float bias;
    int kind, orel;
    if (o < 64)       { wrow = Wq + o * C_;          bias = bq[o];        kind = 0; orel = o; }
    else if (o < 128) { wrow = Wk + (o - 64) * C_;   bias = bk[o - 64];   kind = 1; orel = o - 64; }
    else              { wrow = Wv + (o - 128) * C_;  bias = bv[o - 128];  kind = 2; orel = o - 128; }

    // B-fragments: W[o][ks*32 + quad*8 .. +7] -> bf16
    short8 bf[4];
#pragma unroll
    for (int ks = 0; ks < 4; ++ks) {
      const float* p = wrow + ks * 32 + quad * 8;
      short8 t;
#pragma unroll
      for (int j = 0; j < 8; ++j) t[j] = f2bf(p[j]);
      bf[ks] = t;
    }

    f32x4 acc[4];
#pragma unroll
    for (int mt = 0; mt < 4; ++mt) acc[mt] = (f32x4){0.f, 0.f, 0.f, 0.f};

#pragma unroll
    for (int mt = 0; mt < 4; ++mt) {
#pragma unroll
      for (int ks = 0; ks < 4; ++ks) {
        short8 af = *(const short8*)&xT[(mt * 16 + l16) * 136 + ks * 32 + quad * 8];
        acc[mt] = __builtin_amdgcn_mfma_f32_16x16x32_bf16(af, bf[ks], acc[mt], 0, 0, 0);
      }
    }

    // store: C-layout row = quad*4 + reg (n), col = l16 (o)
#pragma unroll
    for (int mt = 0; mt < 4; ++mt) {
#pragma unroll
      for (int r = 0; r < 4; ++r) {
        const int n = n0 + mt * 16 + quad * 4 + r;
        const short s = f2bf(acc[mt][r] + bias);
        if (kind == 0)      qb[((size_t)b * N_ + n) * 64 + orel] = s;
        else if (kind == 1) kb[((size_t)b * N_ + n) * 64 + orel] = s;
        else                vb[((size_t)b * C_ + orel) * N_ + n] = s;
      }
    }
  }
}

// ---------------------------------------------------------------------------
// Kernel 2: flash attention + fused residual epilogue.
// grid = B * (N/64) = 256 blocks, 256 threads (4 waves; wave owns 16 Q-rows).
// No __syncthreads in the K-loop: waves fully independent.
// ---------------------------------------------------------------------------
__global__ __launch_bounds__(256) void attn_kernel(
    const float* __restrict__ x, const float* __restrict__ gamma,
    const short* __restrict__ qb, const short* __restrict__ kb,
    const short* __restrict__ vb, float* __restrict__ out)
{
  // per-wave arena: max(P bf16 16x136 = 4352B, O f32 16x130 = 8320B)
  __shared__ __align__(16) char arena[4 * 8320];

  const int tid  = threadIdx.x;
  const int b    = blockIdx.x >> 6;
  const int m0   = (blockIdx.x & 63) << 6;
  const int w    = tid >> 6, lane = tid & 63, quad = lane >> 4, l16 = lane & 15;
  const int rbase = m0 + w * 16;

  short* pw = (short*)(arena + w * 8320);
  float* Of = (float*)(arena + w * 8320);

  // Q A-fragments (held in regs for the whole K-loop)
  short8 qa[2];
#pragma unroll
  for (int kk = 0; kk < 2; ++kk)
    qa[kk] = *(const short8*)&qb[((size_t)b * N_ + rbase + l16) * 64 + kk * 32 + quad * 8];

  float m_run[4], l_run[4];
#pragma unroll
  for (int r = 0; r < 4; ++r) { m_run[r] = -INFINITY; l_run[r] = 0.f; }
  f32x4 accO[8];
#pragma unroll
  for (int ct = 0; ct < 8; ++ct) accO[ct] = (f32x4){0.f, 0.f, 0.f, 0.f};

  for (int kt = 0; kt < 32; ++kt) {
    const int kbase = kt * 128;

    // ---- S = Q K^T * scale : 8 col-tiles of 16 keys, K-dim 64 = 2 MFMA steps
    float sv[8][4];
#pragma unroll
    for (int ct = 0; ct < 8; ++ct) {
      f32x4 s = (f32x4){0.f, 0.f, 0.f, 0.f};
#pragma unroll
      for (int kk = 0; kk < 2; ++kk) {
        short8 kf = *(const short8*)&kb[((size_t)b * N_ + kbase + ct * 16 + l16) * 64 + kk * 32 + quad * 8];
        s = __builtin_amdgcn_mfma_f32_16x16x32_bf16(qa[kk], kf, s, 0, 0, 0);
      }
#pragma unroll
      for (int r = 0; r < 4; ++r) sv[ct][r] = s[r] * 0.125f;
    }

    // ---- online softmax (rows of a quad live in that quad's 16 lanes)
    float alpha[4];
#pragma unroll
    for (int r = 0; r < 4; ++r) {
      float mx = sv[0][r];
#pragma unroll
      for (int ct = 1; ct < 8; ++ct) mx = fmaxf(mx, sv[ct][r]);
      mx = fmaxf(mx, __shfl_xor(mx, 1));
      mx = fmaxf(mx, __shfl_xor(mx, 2));
      mx = fmaxf(mx, __shfl_xor(mx, 4));
      mx = fmaxf(mx, __shfl_xor(mx, 8));
      const float mn = fmaxf(m_run[r], mx);
      alpha[r] = __expf(m_run[r] - mn);
      m_run[r] = mn;
    }
#pragma unroll
    for (int r = 0; r < 4; ++r) {
      float rs = 0.f;
#pragma unroll
      for (int ct = 0; ct < 8; ++ct) {
        const float p = __expf(sv[ct][r] - m_run[r]);
        sv[ct][r] = p;
        rs += p;
      }
      rs += __shfl_xor(rs, 1);
      rs += __shfl_xor(rs, 2);
      rs += __shfl_xor(rs, 4);
      rs += __shfl_xor(rs, 8);
      l_run[r] = l_run[r] * alpha[r] + rs;
    }
#pragma unroll
    for (int ct = 0; ct < 8; ++ct)
#pragma unroll
      for (int r = 0; r < 4; ++r) accO[ct][r] *= alpha[r];

    // ---- P (C-layout) -> LDS -> A-layout fragments
#pragma unroll
    for (int ct = 0; ct < 8; ++ct)
#pragma unroll
      for (int r = 0; r < 4; ++r)
        pw[(quad * 4 + r) * 136 + ct * 16 + l16] = f2bf(sv[ct][r]);

    short8 pa[4];
#pragma unroll
    for (int ks = 0; ks < 4; ++ks)
      pa[ks] = *(const short8*)&pw[l16 * 136 + ks * 32 + quad * 8];

    // ---- O += P V : V-frags contiguous from [C][N] layout
#pragma unroll
    for (int ct = 0; ct < 8; ++ct) {
#pragma unroll
      for (int ks = 0; ks < 4; ++ks) {
        short8 vf = *(const short8*)&vb[((size_t)b * C_ + ct * 16 + l16) * N_ + kbase + ks * 32 + quad * 8];
        accO[ct] = __builtin_amdgcn_mfma_f32_16x16x32_bf16(pa[ks], vf, accO[ct], 0, 0, 0);
      }
    }
  }

  // ---- epilogue: normalize, transpose via LDS, out = x + gamma * O
  float inv[4];
#pragma unroll
  for (int r = 0; r < 4; ++r) inv[r] = 1.f / l_run[r];
#pragma unroll
  for (int ct = 0; ct < 8; ++ct)
#pragma unroll
    for (int r = 0; r < 4; ++r)
      Of[(quad * 4 + r) * 130 + ct * 16 + l16] = accO[ct][r] * inv[r];

  const float g = gamma[0];
#pragma unroll
  for (int c0 = 0; c0 < 128; c0 += 4) {
    const int cc = c0 + quad;
    const float ov = Of[l16 * 130 + cc];
    const size_t idx = ((size_t)b * C_ + cc) * N_ + rbase + l16;
    out[idx] = x[idx] + g * ov;
  }
}

// ---------------------------------------------------------------------------
extern "C" void kernel_launch(void* const* d_in, const int* in_sizes, int n_in,
                              void* d_out, int out_size, void* d_ws, size_t ws_size,
                              hipStream_t stream) {
  const float* x     = (const float*)d_in[0];
  const float* Wq    = (const float*)d_in[1];
  const float* bq    = (const float*)d_in[2];
  const float* Wk    = (const float*)d_in[3];
  const float* bk    = (const float*)d_in[4];
  const float* Wv    = (const float*)d_in[5];
  const float* bv    = (const float*)d_in[6];
  const float* gamma = (const float*)d_in[7];
  float* out = (float*)d_out;

  short* qb = (short*)d_ws;                       // [4][4096][64]  bf16 = 2 MB
  short* kb = qb + (size_t)B_ * N_ * INNER_;      // [4][4096][64]  bf16 = 2 MB
  short* vb = kb + (size_t)B_ * N_ * INNER_;      // [4][128][4096] bf16 = 4 MB

  qkv_kernel<<<B_ * (N_ / 64), 256, 0, stream>>>(x, Wq, bq, Wk, bk, Wv, bv, qb, kb, vb);
  attn_kernel<<<B_ * (N_ / 64), 256, 0, stream>>>(x, gamma, qb, kb, vb, out);
}